// Round 1
// baseline (285.783 us; speedup 1.0000x reference)
//
#include <hip/hip_runtime.h>
#include <math.h>

// Problem constants (fixed by setup_inputs)
#define K_  99
#define B_  256
#define T_  2
#define N_  8192
#define TA_ 16

constexpr float DROP_P = 1.0f / 64.0f;
constexpr float PI_F   = 3.14159265358979323846f;   // rounds to 0x40490FDB == float32(np.pi)

// flat output offsets (concatenated in return order)
constexpr int PC_ELEMS = B_ * T_ * N_ * 6;          // 25165824
constexpr int OUT_POS  = PC_ELEMS;                  // (B,T,3)
constexpr int OUT_QUAT = OUT_POS + B_ * T_ * 3;     // (B,T,4)
constexpr int OUT_NACT = OUT_QUAT + B_ * T_ * 4;    // (B,TA,10)

// ---------------------------------------------------------------------------
// Kernel 1: pick idx (first k whose rotation keeps everything in [-1,1]),
// then write per-b (cos,sin) of the chosen Z-rotation into ws.
// One block, 256 threads (= B).
// ---------------------------------------------------------------------------
__global__ __launch_bounds__(B_)
void select_kernel(const float* __restrict__ pos,      // (B,T,3)
                   const float* __restrict__ nact,     // (B,TA,10)
                   const float* __restrict__ angles,   // (K,B,3)
                   const float* __restrict__ dropu,    // (K,B)
                   float2* __restrict__ cs)            // (B,) output
{
    const int b = threadIdx.x;

    float px[T_], py[T_], pz[T_];
    #pragma unroll
    for (int t = 0; t < T_; ++t) {
        px[t] = pos[(b * T_ + t) * 3 + 0];
        py[t] = pos[(b * T_ + t) * 3 + 1];
        pz[t] = pos[(b * T_ + t) * 3 + 2];
    }
    float ax[TA_], ay[TA_];
    #pragma unroll
    for (int a = 0; a < TA_; ++a) {
        ax[a] = nact[(b * TA_ + a) * 10 + 0];
        ay[a] = nact[(b * TA_ + a) * 10 + 1];
    }

    unsigned long long fail0 = 0ull, fail1 = 0ull;
    for (int k = 0; k < K_; ++k) {
        const float u  = angles[(k * B_ + b) * 3 + 2];
        const float du = dropu[k * B_ + b];
        const float a2 = (du < DROP_P) ? 0.0f : (u - 0.5f) * PI_F;
        const float c = cosf(a2), s = sinf(a2);
        bool okb = true;
        #pragma unroll
        for (int t = 0; t < T_; ++t) {
            const float rx = c * px[t] - s * py[t];
            const float ry = s * px[t] + c * py[t];
            okb = okb && (rx >= -1.0f) && (rx <= 1.0f)
                      && (ry >= -1.0f) && (ry <= 1.0f)
                      && (pz[t] >= -1.0f) && (pz[t] <= 1.0f);
        }
        #pragma unroll
        for (int a = 0; a < TA_; ++a) {
            const float rx = c * ax[a] - s * ay[a];
            const float ry = s * ax[a] + c * ay[a];
            okb = okb && (rx >= -1.0f) && (rx <= 1.0f)
                      && (ry >= -1.0f) && (ry <= 1.0f);
        }
        if (!okb) {
            if (k < 64) fail0 |= (1ull << k);
            else        fail1 |= (1ull << (k - 64));
        }
    }

    __shared__ unsigned long long sf[2];
    if (threadIdx.x == 0) { sf[0] = 0ull; sf[1] = 0ull; }
    __syncthreads();
    atomicOr(&sf[0], fail0);
    atomicOr(&sf[1], fail1);
    __syncthreads();

    const unsigned long long ok0 = ~sf[0];                                    // k in [0,64)
    const unsigned long long ok1 = (~sf[1]) & ((1ull << (K_ - 64)) - 1ull);   // k in [64,99)
    int idx;
    if (ok0)      idx = __builtin_ctzll(ok0);
    else if (ok1) idx = 64 + __builtin_ctzll(ok1);
    else          idx = K_ - 1;

    const float u  = angles[(idx * B_ + b) * 3 + 2];
    const float du = dropu[idx * B_ + b];
    const float a2 = (du < DROP_P) ? 0.0f : (u - 0.5f) * PI_F;
    cs[b] = make_float2(cosf(a2), sinf(a2));
}

// ---------------------------------------------------------------------------
// Kernel 2: rotate point cloud xyz, pass through features.
// Dense float4 mapping: float4 g covers floats [4g,4g+4) of the (...,6)
// layout; pattern period is 3 float4s (= 2 points):
//   role 0: [x,y,z,f0]  -> rotate (.x,.y)
//   role 1: [f1,f2,x,y] -> rotate (.z,.w)
//   role 2: [z,f0,f1,f2]-> passthrough
// Fully coalesced 16B/lane loads and stores.
// ---------------------------------------------------------------------------
__global__ __launch_bounds__(256)
void pc_kernel(const float4* __restrict__ pc,
               const float2* __restrict__ cs,
               float4* __restrict__ out)
{
    const int g = blockIdx.x * blockDim.x + threadIdx.x;  // [0, PC_ELEMS/4)
    const int b = g / (T_ * N_ * 6 / 4);                  // 24576 float4 per b
    const float2 csv = cs[b];
    const float c = csv.x, s = csv.y;

    float4 f = pc[g];
    const int role = g % 3;

    const float rx0 = c * f.x - s * f.y;   // role 0 rotation
    const float ry0 = s * f.x + c * f.y;
    const float rx1 = c * f.z - s * f.w;   // role 1 rotation
    const float ry1 = s * f.z + c * f.w;

    if (role == 0) { f.x = rx0; f.y = ry0; }
    if (role == 1) { f.z = rx1; f.w = ry1; }
    out[g] = f;
}

// ---------------------------------------------------------------------------
// Kernel 3: small outputs — rotated_pos, rotated_quat, rotated_naction.
// One thread per (b,ta); threads with ta<T also handle the (b,t) pos/quat.
// ---------------------------------------------------------------------------
__global__ __launch_bounds__(256)
void small_kernel(const float* __restrict__ pos,    // (B,T,3)
                  const float* __restrict__ quat,   // (B,T,4) xyzw
                  const float* __restrict__ nact,   // (B,TA,10)
                  const float2* __restrict__ cs,
                  float* __restrict__ out)
{
    const int tid = blockIdx.x * blockDim.x + threadIdx.x;
    if (tid >= B_ * TA_) return;
    const int b = tid / TA_;
    const int a = tid % TA_;
    const float2 csv = cs[b];
    const float c = csv.x, s = csv.y;

    // ----- rotated_naction (b, a) -----
    const float* nr = nact + (b * TA_ + a) * 10;
    const float apx = nr[0], apy = nr[1], apz = nr[2];

    // rot6d -> matrix (rows b1,b2,b3), Gram-Schmidt
    const float a1x = nr[3], a1y = nr[4], a1z = nr[5];
    const float a2x = nr[6], a2y = nr[7], a2z = nr[8];
    const float n1  = sqrtf(a1x * a1x + a1y * a1y + a1z * a1z);
    const float b1x = a1x / n1, b1y = a1y / n1, b1z = a1z / n1;
    const float d   = b1x * a2x + b1y * a2y + b1z * a2z;
    const float t2x = a2x - d * b1x, t2y = a2y - d * b1y, t2z = a2z - d * b1z;
    const float n2  = sqrtf(t2x * t2x + t2y * t2y + t2z * t2z);
    const float b2x = t2x / n2, b2y = t2y / n2, b2z = t2z / n2;
    const float b3x = b1y * b2z - b1z * b2y;
    const float b3y = b1z * b2x - b1x * b2z;
    const float b3z = b1x * b2y - b1y * b2x;

    // R @ arot, R = RZ: row0 = c*b1 - s*b2 ; row1 = s*b1 + c*b2 ; (row2 = b3 unused)
    float* no = out + OUT_NACT + (b * TA_ + a) * 10;
    no[0] = c * apx - s * apy;
    no[1] = s * apx + c * apy;
    no[2] = apz;
    no[3] = c * b1x - s * b2x;
    no[4] = c * b1y - s * b2y;
    no[5] = c * b1z - s * b2z;
    no[6] = s * b1x + c * b2x;
    no[7] = s * b1y + c * b2y;
    no[8] = s * b1z + c * b2z;
    no[9] = nr[9];
    (void)b3x; (void)b3y; (void)b3z;

    // ----- rotated_pos / rotated_quat for t = a < T -----
    if (a < T_) {
        const int t = a;
        const float* pr = pos + (b * T_ + t) * 3;
        float* po = out + OUT_POS + (b * T_ + t) * 3;
        po[0] = c * pr[0] - s * pr[1];
        po[1] = s * pr[0] + c * pr[1];
        po[2] = pr[2];

        // quat (xyzw input) -> wxyz
        const float* qp = quat + (b * T_ + t) * 4;
        const float qx = qp[0], qy = qp[1], qz = qp[2], qw = qp[3];
        const float ts = 2.0f / (qw * qw + qx * qx + qy * qy + qz * qz);
        // quat_to_matrix
        const float m00 = 1.0f - ts * (qy * qy + qz * qz);
        const float m01 = ts * (qx * qy - qz * qw);
        const float m02 = ts * (qx * qz + qy * qw);
        const float m10 = ts * (qx * qy + qz * qw);
        const float m11 = 1.0f - ts * (qx * qx + qz * qz);
        const float m12 = ts * (qy * qz - qx * qw);
        const float m20 = ts * (qx * qz - qy * qw);
        const float m21 = ts * (qy * qz + qx * qw);
        const float m22 = 1.0f - ts * (qx * qx + qy * qy);
        // M = RZ @ m
        const float M00 = c * m00 - s * m10, M01 = c * m01 - s * m11, M02 = c * m02 - s * m12;
        const float M10 = s * m00 + c * m10, M11 = s * m01 + c * m11, M12 = s * m02 + c * m12;
        const float M20 = m20, M21 = m21, M22 = m22;

        // matrix_to_quat (wxyz), first-max argmax semantics
        const float qa0 = sqrtf(fmaxf(1.0f + M00 + M11 + M22, 0.0f));
        const float qa1 = sqrtf(fmaxf(1.0f + M00 - M11 - M22, 0.0f));
        const float qa2 = sqrtf(fmaxf(1.0f - M00 + M11 - M22, 0.0f));
        const float qa3 = sqrtf(fmaxf(1.0f - M00 - M11 + M22, 0.0f));
        int best = 0; float bv = qa0;
        if (qa1 > bv) { best = 1; bv = qa1; }
        if (qa2 > bv) { best = 2; bv = qa2; }
        if (qa3 > bv) { best = 3; bv = qa3; }
        float cw, cx, cy, cz;
        if      (best == 0) { cw = qa0 * qa0; cx = M21 - M12; cy = M02 - M20; cz = M10 - M01; }
        else if (best == 1) { cw = M21 - M12; cx = qa1 * qa1; cy = M10 + M01; cz = M02 + M20; }
        else if (best == 2) { cw = M02 - M20; cx = M10 + M01; cy = qa2 * qa2; cz = M12 + M21; }
        else                { cw = M10 - M01; cx = M20 + M02; cy = M21 + M12; cz = qa3 * qa3; }
        const float denom = 2.0f * fmaxf(bv, 0.1f);
        float* qo = out + OUT_QUAT + (b * T_ + t) * 4;
        qo[0] = cx / denom;   // wxyz -> xyzw reorder
        qo[1] = cy / denom;
        qo[2] = cz / denom;
        qo[3] = cw / denom;
    }
}

// ---------------------------------------------------------------------------
extern "C" void kernel_launch(void* const* d_in, const int* in_sizes, int n_in,
                              void* d_out, int out_size, void* d_ws, size_t ws_size,
                              hipStream_t stream)
{
    const float* pc     = (const float*)d_in[0];
    const float* pos    = (const float*)d_in[1];
    const float* quat   = (const float*)d_in[2];
    const float* nact   = (const float*)d_in[3];
    const float* angles = (const float*)d_in[4];
    const float* dropu  = (const float*)d_in[5];
    float*  out = (float*)d_out;
    float2* cs  = (float2*)d_ws;   // B_ float2 = 2 KiB scratch

    select_kernel<<<1, B_, 0, stream>>>(pos, nact, angles, dropu, cs);

    constexpr int n4 = PC_ELEMS / 4;            // 6,291,456 float4s
    pc_kernel<<<n4 / 256, 256, 0, stream>>>((const float4*)pc, cs, (float4*)out);

    small_kernel<<<(B_ * TA_) / 256, 256, 0, stream>>>(pos, quat, nact, cs, out);
}

// Round 2
// 195.139 us; speedup vs baseline: 1.4645x; 1.4645x over previous
//
#include <hip/hip_runtime.h>
#include <math.h>

// Problem constants (fixed by setup_inputs)
#define K_  99
#define B_  256
#define T_  2
#define N_  8192
#define TA_ 16

constexpr float DROP_P = 1.0f / 64.0f;
constexpr float PI_F   = 3.14159265358979323846f;   // rounds to 0x40490FDB == float32(np.pi)

// flat output offsets (concatenated in return order)
constexpr int PC_ELEMS = B_ * T_ * N_ * 6;          // 25165824
constexpr int OUT_POS  = PC_ELEMS;                  // (B,T,3)
constexpr int OUT_QUAT = OUT_POS + B_ * T_ * 3;     // (B,T,4)
constexpr int OUT_NACT = OUT_QUAT + B_ * T_ * 4;    // (B,TA,10)

// ws layout: float2 cs[B_] at 0 (2 KiB), int ok[K_] at byte 2048.
// ok[] fully written by ok_kernel every call; cs[] by finalize_kernel —
// no dependence on pre-zeroed ws (harness poisons it 0xAA).

// ---------------------------------------------------------------------------
// Kernel A: one block per k, one thread per b. ok[k] = AND_b ok(k,b).
// ---------------------------------------------------------------------------
__global__ __launch_bounds__(B_)
void ok_kernel(const float* __restrict__ pos,      // (B,T,3)
               const float* __restrict__ nact,     // (B,TA,10)
               const float* __restrict__ angles,   // (K,B,3)
               const float* __restrict__ dropu,    // (K,B)
               int* __restrict__ ok)               // (K,)
{
    const int k = blockIdx.x;
    const int b = threadIdx.x;

    const float u  = angles[(k * B_ + b) * 3 + 2];
    const float du = dropu[k * B_ + b];
    const float a2 = (du < DROP_P) ? 0.0f : (u - 0.5f) * PI_F;
    const float c = cosf(a2), s = sinf(a2);

    bool okb = true;
    #pragma unroll
    for (int t = 0; t < T_; ++t) {
        const float x = pos[(b * T_ + t) * 3 + 0];
        const float y = pos[(b * T_ + t) * 3 + 1];
        const float z = pos[(b * T_ + t) * 3 + 2];
        const float rx = c * x - s * y;
        const float ry = s * x + c * y;
        okb = okb && (rx >= -1.0f) && (rx <= 1.0f)
                  && (ry >= -1.0f) && (ry <= 1.0f)
                  && (z  >= -1.0f) && (z  <= 1.0f);
    }
    #pragma unroll
    for (int a = 0; a < TA_; ++a) {
        const float x = nact[(b * TA_ + a) * 10 + 0];
        const float y = nact[(b * TA_ + a) * 10 + 1];
        const float rx = c * x - s * y;
        const float ry = s * x + c * y;
        okb = okb && (rx >= -1.0f) && (rx <= 1.0f)
                  && (ry >= -1.0f) && (ry <= 1.0f);
    }

    const unsigned long long m = __ballot(okb);
    __shared__ int wave_ok[4];
    if ((threadIdx.x & 63) == 0) wave_ok[threadIdx.x >> 6] = (m == ~0ull) ? 1 : 0;
    __syncthreads();
    if (threadIdx.x == 0)
        ok[k] = wave_ok[0] & wave_ok[1] & wave_ok[2] & wave_ok[3];
}

// ---------------------------------------------------------------------------
// Kernel B: idx = first k with ok[k] (else K-1); write per-b (cos,sin).
// One block, 256 threads.
// ---------------------------------------------------------------------------
__global__ __launch_bounds__(B_)
void finalize_kernel(const int* __restrict__ ok,
                     const float* __restrict__ angles,
                     const float* __restrict__ dropu,
                     float2* __restrict__ cs)
{
    __shared__ int sidx;
    if (threadIdx.x == 0) sidx = K_ - 1;
    __syncthreads();
    const int k = threadIdx.x;
    if (k < K_ && ok[k]) atomicMin(&sidx, k);
    __syncthreads();
    const int idx = sidx;

    const int b = threadIdx.x;
    const float u  = angles[(idx * B_ + b) * 3 + 2];
    const float du = dropu[idx * B_ + b];
    const float a2 = (du < DROP_P) ? 0.0f : (u - 0.5f) * PI_F;
    cs[b] = make_float2(cosf(a2), sinf(a2));
}

// ---------------------------------------------------------------------------
// Kernel 2: rotate point cloud xyz, pass through features.
// Dense float4 mapping over the (...,6) layout; period 3 float4s (=2 points):
//   role 0: [x,y,z,f0]  -> rotate (.x,.y)
//   role 1: [f1,f2,x,y] -> rotate (.z,.w)
//   role 2: [z,f0,f1,f2]-> passthrough
// ---------------------------------------------------------------------------
__global__ __launch_bounds__(256)
void pc_kernel(const float4* __restrict__ pc,
               const float2* __restrict__ cs,
               float4* __restrict__ out)
{
    const int g = blockIdx.x * blockDim.x + threadIdx.x;  // [0, PC_ELEMS/4)
    const int b = g / (T_ * N_ * 6 / 4);                  // 24576 float4 per b
    const float2 csv = cs[b];
    const float c = csv.x, s = csv.y;

    float4 f = pc[g];
    const int role = g % 3;

    const float rx0 = c * f.x - s * f.y;   // role 0 rotation
    const float ry0 = s * f.x + c * f.y;
    const float rx1 = c * f.z - s * f.w;   // role 1 rotation
    const float ry1 = s * f.z + c * f.w;

    if (role == 0) { f.x = rx0; f.y = ry0; }
    if (role == 1) { f.z = rx1; f.w = ry1; }
    out[g] = f;
}

// ---------------------------------------------------------------------------
// Kernel 3: small outputs — rotated_pos, rotated_quat, rotated_naction.
// One thread per (b,ta); threads with ta<T also handle the (b,t) pos/quat.
// ---------------------------------------------------------------------------
__global__ __launch_bounds__(256)
void small_kernel(const float* __restrict__ pos,    // (B,T,3)
                  const float* __restrict__ quat,   // (B,T,4) xyzw
                  const float* __restrict__ nact,   // (B,TA,10)
                  const float2* __restrict__ cs,
                  float* __restrict__ out)
{
    const int tid = blockIdx.x * blockDim.x + threadIdx.x;
    if (tid >= B_ * TA_) return;
    const int b = tid / TA_;
    const int a = tid % TA_;
    const float2 csv = cs[b];
    const float c = csv.x, s = csv.y;

    // ----- rotated_naction (b, a) -----
    const float* nr = nact + (b * TA_ + a) * 10;
    const float apx = nr[0], apy = nr[1], apz = nr[2];

    // rot6d -> matrix (rows b1,b2,b3), Gram-Schmidt
    const float a1x = nr[3], a1y = nr[4], a1z = nr[5];
    const float a2x = nr[6], a2y = nr[7], a2z = nr[8];
    const float n1  = sqrtf(a1x * a1x + a1y * a1y + a1z * a1z);
    const float b1x = a1x / n1, b1y = a1y / n1, b1z = a1z / n1;
    const float d   = b1x * a2x + b1y * a2y + b1z * a2z;
    const float t2x = a2x - d * b1x, t2y = a2y - d * b1y, t2z = a2z - d * b1z;
    const float n2  = sqrtf(t2x * t2x + t2y * t2y + t2z * t2z);
    const float b2x = t2x / n2, b2y = t2y / n2, b2z = t2z / n2;

    // R @ arot, R = RZ: row0 = c*b1 - s*b2 ; row1 = s*b1 + c*b2
    float* no = out + OUT_NACT + (b * TA_ + a) * 10;
    no[0] = c * apx - s * apy;
    no[1] = s * apx + c * apy;
    no[2] = apz;
    no[3] = c * b1x - s * b2x;
    no[4] = c * b1y - s * b2y;
    no[5] = c * b1z - s * b2z;
    no[6] = s * b1x + c * b2x;
    no[7] = s * b1y + c * b2y;
    no[8] = s * b1z + c * b2z;
    no[9] = nr[9];

    // ----- rotated_pos / rotated_quat for t = a < T -----
    if (a < T_) {
        const int t = a;
        const float* pr = pos + (b * T_ + t) * 3;
        float* po = out + OUT_POS + (b * T_ + t) * 3;
        po[0] = c * pr[0] - s * pr[1];
        po[1] = s * pr[0] + c * pr[1];
        po[2] = pr[2];

        // quat (xyzw input) -> wxyz
        const float* qp = quat + (b * T_ + t) * 4;
        const float qx = qp[0], qy = qp[1], qz = qp[2], qw = qp[3];
        const float ts = 2.0f / (qw * qw + qx * qx + qy * qy + qz * qz);
        // quat_to_matrix
        const float m00 = 1.0f - ts * (qy * qy + qz * qz);
        const float m01 = ts * (qx * qy - qz * qw);
        const float m02 = ts * (qx * qz + qy * qw);
        const float m10 = ts * (qx * qy + qz * qw);
        const float m11 = 1.0f - ts * (qx * qx + qz * qz);
        const float m12 = ts * (qy * qz - qx * qw);
        const float m20 = ts * (qx * qz - qy * qw);
        const float m21 = ts * (qy * qz + qx * qw);
        const float m22 = 1.0f - ts * (qx * qx + qy * qy);
        // M = RZ @ m
        const float M00 = c * m00 - s * m10, M01 = c * m01 - s * m11, M02 = c * m02 - s * m12;
        const float M10 = s * m00 + c * m10, M11 = s * m01 + c * m11, M12 = s * m02 + c * m12;
        const float M20 = m20, M21 = m21, M22 = m22;

        // matrix_to_quat (wxyz), first-max argmax semantics
        const float qa0 = sqrtf(fmaxf(1.0f + M00 + M11 + M22, 0.0f));
        const float qa1 = sqrtf(fmaxf(1.0f + M00 - M11 - M22, 0.0f));
        const float qa2 = sqrtf(fmaxf(1.0f - M00 + M11 - M22, 0.0f));
        const float qa3 = sqrtf(fmaxf(1.0f - M00 - M11 + M22, 0.0f));
        int best = 0; float bv = qa0;
        if (qa1 > bv) { best = 1; bv = qa1; }
        if (qa2 > bv) { best = 2; bv = qa2; }
        if (qa3 > bv) { best = 3; bv = qa3; }
        float cw, cx, cy, cz;
        if      (best == 0) { cw = qa0 * qa0; cx = M21 - M12; cy = M02 - M20; cz = M10 - M01; }
        else if (best == 1) { cw = M21 - M12; cx = qa1 * qa1; cy = M10 + M01; cz = M02 + M20; }
        else if (best == 2) { cw = M02 - M20; cx = M10 + M01; cy = qa2 * qa2; cz = M12 + M21; }
        else                { cw = M10 - M01; cx = M20 + M02; cy = M21 + M12; cz = qa3 * qa3; }
        const float denom = 2.0f * fmaxf(bv, 0.1f);
        float* qo = out + OUT_QUAT + (b * T_ + t) * 4;
        qo[0] = cx / denom;   // wxyz -> xyzw reorder
        qo[1] = cy / denom;
        qo[2] = cz / denom;
        qo[3] = cw / denom;
    }
}

// ---------------------------------------------------------------------------
extern "C" void kernel_launch(void* const* d_in, const int* in_sizes, int n_in,
                              void* d_out, int out_size, void* d_ws, size_t ws_size,
                              hipStream_t stream)
{
    const float* pc     = (const float*)d_in[0];
    const float* pos    = (const float*)d_in[1];
    const float* quat   = (const float*)d_in[2];
    const float* nact   = (const float*)d_in[3];
    const float* angles = (const float*)d_in[4];
    const float* dropu  = (const float*)d_in[5];
    float*  out = (float*)d_out;
    float2* cs  = (float2*)d_ws;                       // B_ float2 = 2 KiB
    int*    ok  = (int*)((char*)d_ws + 2048);          // K_ ints

    ok_kernel<<<K_, B_, 0, stream>>>(pos, nact, angles, dropu, ok);
    finalize_kernel<<<1, B_, 0, stream>>>(ok, angles, dropu, cs);

    constexpr int n4 = PC_ELEMS / 4;                   // 6,291,456 float4s
    pc_kernel<<<n4 / 256, 256, 0, stream>>>((const float4*)pc, cs, (float4*)out);

    small_kernel<<<(B_ * TA_) / 256, 256, 0, stream>>>(pos, quat, nact, cs, out);
}

// Round 3
// 190.548 us; speedup vs baseline: 1.4998x; 1.0241x over previous
//
#include <hip/hip_runtime.h>
#include <math.h>

// Problem constants (fixed by setup_inputs)
#define K_  99
#define B_  256
#define T_  2
#define N_  8192
#define TA_ 16

constexpr float DROP_P = 1.0f / 64.0f;
constexpr float PI_F   = 3.14159265358979323846f;   // float32(np.pi)

// flat output offsets (concatenated in return order)
constexpr int PC_ELEMS = B_ * T_ * N_ * 6;          // 25165824
constexpr int OUT_POS  = PC_ELEMS;                  // (B,T,3)
constexpr int OUT_QUAT = OUT_POS + B_ * T_ * 3;     // (B,T,4)
constexpr int OUT_NACT = OUT_QUAT + B_ * T_ * 4;    // (B,TA,10)

typedef float f4v __attribute__((ext_vector_type(4)));

// ws layout: float2 cs[B_] at 0 (2 KiB), int ok[K_] at byte 2048.
// Both fully rewritten every call (harness poisons ws with 0xAA).

// ---------------------------------------------------------------------------
// Kernel A: one block per k, one thread per b. ok[k] = AND_b ok(k,b).
// ---------------------------------------------------------------------------
__global__ __launch_bounds__(B_)
void ok_kernel(const float* __restrict__ pos,      // (B,T,3)
               const float* __restrict__ nact,     // (B,TA,10)
               const float* __restrict__ angles,   // (K,B,3)
               const float* __restrict__ dropu,    // (K,B)
               int* __restrict__ ok)               // (K,)
{
    const int k = blockIdx.x;
    const int b = threadIdx.x;

    const float u  = angles[(k * B_ + b) * 3 + 2];
    const float du = dropu[k * B_ + b];
    const float a2 = (du < DROP_P) ? 0.0f : (u - 0.5f) * PI_F;
    const float c = cosf(a2), s = sinf(a2);

    bool okb = true;
    #pragma unroll
    for (int t = 0; t < T_; ++t) {
        const float x = pos[(b * T_ + t) * 3 + 0];
        const float y = pos[(b * T_ + t) * 3 + 1];
        const float z = pos[(b * T_ + t) * 3 + 2];
        const float rx = c * x - s * y;
        const float ry = s * x + c * y;
        okb = okb && (rx >= -1.0f) && (rx <= 1.0f)
                  && (ry >= -1.0f) && (ry <= 1.0f)
                  && (z  >= -1.0f) && (z  <= 1.0f);
    }
    #pragma unroll
    for (int a = 0; a < TA_; ++a) {
        const float x = nact[(b * TA_ + a) * 10 + 0];
        const float y = nact[(b * TA_ + a) * 10 + 1];
        const float rx = c * x - s * y;
        const float ry = s * x + c * y;
        okb = okb && (rx >= -1.0f) && (rx <= 1.0f)
                  && (ry >= -1.0f) && (ry <= 1.0f);
    }

    const unsigned long long m = __ballot(okb);
    __shared__ int wave_ok[4];
    if ((threadIdx.x & 63) == 0) wave_ok[threadIdx.x >> 6] = (m == ~0ull) ? 1 : 0;
    __syncthreads();
    if (threadIdx.x == 0)
        ok[k] = wave_ok[0] & wave_ok[1] & wave_ok[2] & wave_ok[3];
}

// ---------------------------------------------------------------------------
// Kernel B: idx = first k with ok[k] (else K-1); write per-b (cos,sin).
// ---------------------------------------------------------------------------
__global__ __launch_bounds__(B_)
void finalize_kernel(const int* __restrict__ ok,
                     const float* __restrict__ angles,
                     const float* __restrict__ dropu,
                     float2* __restrict__ cs)
{
    __shared__ int sidx;
    if (threadIdx.x == 0) sidx = K_ - 1;
    __syncthreads();
    const int k = threadIdx.x;
    if (k < K_ && ok[k]) atomicMin(&sidx, k);
    __syncthreads();
    const int idx = sidx;

    const int b = threadIdx.x;
    const float u  = angles[(idx * B_ + b) * 3 + 2];
    const float du = dropu[idx * B_ + b];
    const float a2 = (du < DROP_P) ? 0.0f : (u - 0.5f) * PI_F;
    cs[b] = make_float2(cosf(a2), sinf(a2));
}

// ---------------------------------------------------------------------------
// Kernel 2: rotate point cloud xyz, pass through features. Streaming:
// nontemporal 16B/lane loads+stores (output ≫ L2, avoid write-allocate
// thrash). b is block-uniform (24576 float4/b = 96 blocks/b) → scalar load
// of cs[b]. role = g%3; 256 ≡ 1 (mod 3) so role = (blockIdx.x+tid)%3.
//   role 0: [x,y,z,f0]  -> rotate (.x,.y)
//   role 1: [f1,f2,x,y] -> rotate (.z,.w)
//   role 2: [z,f0,f1,f2]-> passthrough
// ---------------------------------------------------------------------------
__global__ __launch_bounds__(256)
void pc_kernel(const f4v* __restrict__ pc,
               const float2* __restrict__ cs,
               f4v* __restrict__ out)
{
    const int g = blockIdx.x * 256 + threadIdx.x;   // [0, PC_ELEMS/4)
    const int b = blockIdx.x / 96;                  // uniform per block
    const float2 csv = cs[b];
    const float c = csv.x, s = csv.y;

    f4v f = __builtin_nontemporal_load(&pc[g]);
    const int role = (blockIdx.x + threadIdx.x) % 3;

    const float rx0 = c * f.x - s * f.y;   // role 0 rotation
    const float ry0 = s * f.x + c * f.y;
    const float rx1 = c * f.z - s * f.w;   // role 1 rotation
    const float ry1 = s * f.z + c * f.w;

    if (role == 0) { f.x = rx0; f.y = ry0; }
    if (role == 1) { f.z = rx1; f.w = ry1; }
    __builtin_nontemporal_store(f, &out[g]);
}

// ---------------------------------------------------------------------------
// Kernel 3: small outputs — rotated_pos, rotated_quat, rotated_naction.
// One thread per (b,ta); threads with ta<T also handle the (b,t) pos/quat.
// ---------------------------------------------------------------------------
__global__ __launch_bounds__(256)
void small_kernel(const float* __restrict__ pos,    // (B,T,3)
                  const float* __restrict__ quat,   // (B,T,4) xyzw
                  const float* __restrict__ nact,   // (B,TA,10)
                  const float2* __restrict__ cs,
                  float* __restrict__ out)
{
    const int tid = blockIdx.x * blockDim.x + threadIdx.x;
    if (tid >= B_ * TA_) return;
    const int b = tid / TA_;
    const int a = tid % TA_;
    const float2 csv = cs[b];
    const float c = csv.x, s = csv.y;

    // ----- rotated_naction (b, a) -----
    const float* nr = nact + (b * TA_ + a) * 10;
    const float apx = nr[0], apy = nr[1], apz = nr[2];

    // rot6d -> matrix (rows b1,b2), Gram-Schmidt
    const float a1x = nr[3], a1y = nr[4], a1z = nr[5];
    const float a2x = nr[6], a2y = nr[7], a2z = nr[8];
    const float n1  = sqrtf(a1x * a1x + a1y * a1y + a1z * a1z);
    const float b1x = a1x / n1, b1y = a1y / n1, b1z = a1z / n1;
    const float d   = b1x * a2x + b1y * a2y + b1z * a2z;
    const float t2x = a2x - d * b1x, t2y = a2y - d * b1y, t2z = a2z - d * b1z;
    const float n2  = sqrtf(t2x * t2x + t2y * t2y + t2z * t2z);
    const float b2x = t2x / n2, b2y = t2y / n2, b2z = t2z / n2;

    // R @ arot, R = RZ: row0 = c*b1 - s*b2 ; row1 = s*b1 + c*b2
    float* no = out + OUT_NACT + (b * TA_ + a) * 10;
    no[0] = c * apx - s * apy;
    no[1] = s * apx + c * apy;
    no[2] = apz;
    no[3] = c * b1x - s * b2x;
    no[4] = c * b1y - s * b2y;
    no[5] = c * b1z - s * b2z;
    no[6] = s * b1x + c * b2x;
    no[7] = s * b1y + c * b2y;
    no[8] = s * b1z + c * b2z;
    no[9] = nr[9];

    // ----- rotated_pos / rotated_quat for t = a < T -----
    if (a < T_) {
        const int t = a;
        const float* pr = pos + (b * T_ + t) * 3;
        float* po = out + OUT_POS + (b * T_ + t) * 3;
        po[0] = c * pr[0] - s * pr[1];
        po[1] = s * pr[0] + c * pr[1];
        po[2] = pr[2];

        // quat (xyzw input) -> wxyz
        const float* qp = quat + (b * T_ + t) * 4;
        const float qx = qp[0], qy = qp[1], qz = qp[2], qw = qp[3];
        const float ts = 2.0f / (qw * qw + qx * qx + qy * qy + qz * qz);
        const float m00 = 1.0f - ts * (qy * qy + qz * qz);
        const float m01 = ts * (qx * qy - qz * qw);
        const float m02 = ts * (qx * qz + qy * qw);
        const float m10 = ts * (qx * qy + qz * qw);
        const float m11 = 1.0f - ts * (qx * qx + qz * qz);
        const float m12 = ts * (qy * qz - qx * qw);
        const float m20 = ts * (qx * qz - qy * qw);
        const float m21 = ts * (qy * qz + qx * qw);
        const float m22 = 1.0f - ts * (qx * qx + qy * qy);
        // M = RZ @ m
        const float M00 = c * m00 - s * m10, M01 = c * m01 - s * m11, M02 = c * m02 - s * m12;
        const float M10 = s * m00 + c * m10, M11 = s * m01 + c * m11, M12 = s * m02 + c * m12;
        const float M20 = m20, M21 = m21, M22 = m22;

        // matrix_to_quat (wxyz), first-max argmax semantics
        const float qa0 = sqrtf(fmaxf(1.0f + M00 + M11 + M22, 0.0f));
        const float qa1 = sqrtf(fmaxf(1.0f + M00 - M11 - M22, 0.0f));
        const float qa2 = sqrtf(fmaxf(1.0f - M00 + M11 - M22, 0.0f));
        const float qa3 = sqrtf(fmaxf(1.0f - M00 - M11 + M22, 0.0f));
        int best = 0; float bv = qa0;
        if (qa1 > bv) { best = 1; bv = qa1; }
        if (qa2 > bv) { best = 2; bv = qa2; }
        if (qa3 > bv) { best = 3; bv = qa3; }
        float cw, cx, cy, cz;
        if      (best == 0) { cw = qa0 * qa0; cx = M21 - M12; cy = M02 - M20; cz = M10 - M01; }
        else if (best == 1) { cw = M21 - M12; cx = qa1 * qa1; cy = M10 + M01; cz = M02 + M20; }
        else if (best == 2) { cw = M02 - M20; cx = M10 + M01; cy = qa2 * qa2; cz = M12 + M21; }
        else                { cw = M10 - M01; cx = M20 + M02; cy = M21 + M12; cz = qa3 * qa3; }
        const float denom = 2.0f * fmaxf(bv, 0.1f);
        float* qo = out + OUT_QUAT + (b * T_ + t) * 4;
        qo[0] = cx / denom;   // wxyz -> xyzw reorder
        qo[1] = cy / denom;
        qo[2] = cz / denom;
        qo[3] = cw / denom;
    }
}

// ---------------------------------------------------------------------------
extern "C" void kernel_launch(void* const* d_in, const int* in_sizes, int n_in,
                              void* d_out, int out_size, void* d_ws, size_t ws_size,
                              hipStream_t stream)
{
    const float* pc     = (const float*)d_in[0];
    const float* pos    = (const float*)d_in[1];
    const float* quat   = (const float*)d_in[2];
    const float* nact   = (const float*)d_in[3];
    const float* angles = (const float*)d_in[4];
    const float* dropu  = (const float*)d_in[5];
    float*  out = (float*)d_out;
    float2* cs  = (float2*)d_ws;                       // B_ float2 = 2 KiB
    int*    ok  = (int*)((char*)d_ws + 2048);          // K_ ints

    ok_kernel<<<K_, B_, 0, stream>>>(pos, nact, angles, dropu, ok);
    finalize_kernel<<<1, B_, 0, stream>>>(ok, angles, dropu, cs);

    constexpr int n4 = PC_ELEMS / 4;                   // 6,291,456 float4s
    pc_kernel<<<n4 / 256, 256, 0, stream>>>((const f4v*)pc, cs, (f4v*)out);

    small_kernel<<<(B_ * TA_) / 256, 256, 0, stream>>>(pos, quat, nact, cs, out);
}